// Round 8
// baseline (5109.085 us; speedup 1.0000x reference)
//
#include <hip/hip_runtime.h>
#include <stdint.h>

typedef float   f32x4 __attribute__((ext_vector_type(4)));
typedef float   f32x2 __attribute__((ext_vector_type(2)));
typedef int     i32x4 __attribute__((ext_vector_type(4)));
typedef int     i32x2 __attribute__((ext_vector_type(2)));
typedef __bf16  bf16x8 __attribute__((ext_vector_type(8)));

#define DEV __device__ __forceinline__

// ---------- helpers ----------
DEV uint16_t f2bf(float f){                       // RNE f32->bf16
  uint32_t u = __float_as_uint(f);
  u += 0x7fffu + ((u >> 16) & 1u);
  return (uint16_t)(u >> 16);
}
DEV uint32_t pkbf(float lo, float hi){            // pack 2 bf16 into u32
  uint32_t r;
  asm("v_cvt_pk_bf16_f32 %0, %1, %2" : "=v"(r) : "v"(lo), "v"(hi));
  return r;
}
// byte offset inside a [row][128 bf16] (256B) row with XOR-16B bank swizzle
DEV uint32_t aoff(uint32_t row, uint32_t q){ return (row << 8) + (q ^ ((row & 7u) << 4)); }

DEV f32x4 MFMA(bf16x8 a, bf16x8 b, f32x4 c){
  return __builtin_amdgcn_mfma_f32_16x16x32_bf16(a, b, c, 0, 0, 0);
}
DEV bf16x8 as_bf(i32x4 v){ union { i32x4 i; bf16x8 b; } u; u.i = v; return u.b; }

DEV uint64_t ld_ic64(const void* p){
  return __hip_atomic_load((const uint64_t*)p, __ATOMIC_RELAXED, __HIP_MEMORY_SCOPE_AGENT);
}
DEV void st_ic64(void* p, uint64_t v){
  __hip_atomic_store((uint64_t*)p, v, __ATOMIC_RELAXED, __HIP_MEMORY_SCOPE_AGENT);
}

// ---------- W_out -> per-ht LDS images (Wg) + c0-tile frags (w0f), scaled ----------
// src [128 k][16512 n], n = h*129 + c. c>=1: row r=(c-1)*4+(h&3), image ht=h>>2.
__global__ __launch_bounds__(256) void pose_convW(const float* __restrict__ src,
    uint16_t* __restrict__ Wg, uint16_t* __restrict__ w0f)
{
  __shared__ float tile[32][256];
  const float SC = 2.8853900817779268f;   // 2*log2(e)
  int bk = blockIdx.x & 3, bn = blockIdx.x >> 2;
  int k0 = bk * 32, n0 = bn * 256;
  int t = threadIdx.x;
  for (int r = 0; r < 32; r++){
    int n = n0 + t;
    tile[r][t] = (n < 16512) ? src[(size_t)(k0 + r) * 16512 + n] : 0.f;
  }
  __syncthreads();
  int n = n0 + t;
  if (n < 16512){
    int c = n % 129, hfull = n / 129;
    int ht = hfull >> 2;
    #pragma unroll
    for (int o = 0; o < 4; o++){
      uint32_t w0 = (uint32_t)f2bf(tile[o*8+0][t]*SC) | ((uint32_t)f2bf(tile[o*8+1][t]*SC) << 16);
      uint32_t w1 = (uint32_t)f2bf(tile[o*8+2][t]*SC) | ((uint32_t)f2bf(tile[o*8+3][t]*SC) << 16);
      uint32_t w2 = (uint32_t)f2bf(tile[o*8+4][t]*SC) | ((uint32_t)f2bf(tile[o*8+5][t]*SC) << 16);
      uint32_t w3 = (uint32_t)f2bf(tile[o*8+6][t]*SC) | ((uint32_t)f2bf(tile[o*8+7][t]*SC) << 16);
      i32x4 val = { (int)w0, (int)w1, (int)w2, (int)w3 };
      uint32_t kg = (uint32_t)(k0 + o*8);
      if (c > 0){
        uint32_t r = (uint32_t)(c - 1)*4 + (hfull & 3);
        uint32_t byte = (uint32_t)ht*131072u + r*256u + ((kg*2u) ^ ((r & 7u) << 4));
        *(i32x4*)((char*)Wg + byte) = val;
      } else {
        uint32_t r0 = (uint32_t)(hfull & 3);
        uint32_t byte = (uint32_t)ht*4096u + (kg >> 5)*1024u + (r0 + 16u*((kg >> 3) & 3u))*16u;
        *(i32x4*)((char*)w0f + byte) = val;
      }
    }
  }
}

// ---------- chain weights -> A-frag layout: dst[Mt 8][kb 4][l 64][j 8] ----------
__global__ __launch_bounds__(256) void pose_convC(const float* __restrict__ w_h1,
    const float* __restrict__ w_h2, uint32_t* __restrict__ w1f, uint32_t* __restrict__ w2f)
{
  const float* src = blockIdx.x ? w_h2 : w_h1;
  uint32_t* dst = blockIdx.x ? w2f : w1f;
  int t = threadIdx.x;
  for (int ii = 0; ii < 32; ii++){
    int u = t*32 + ii;
    int p = u & 3, l = (u >> 2) & 63, kb = (u >> 8) & 3, Mt = u >> 10;
    int k = kb*32 + (l >> 4)*8 + 2*p;
    int n = Mt*16 + (l & 15);
    uint32_t v = (uint32_t)f2bf(src[(size_t)k*128 + n]) |
                 ((uint32_t)f2bf(src[(size_t)(k+1)*128 + n]) << 16);
    dst[u] = v;
  }
}

// ---------- bo_f[c'][h], bo_t[h], d0t[b] ----------
__global__ __launch_bounds__(256) void pose_misc(const float* __restrict__ b_out,
    const float* __restrict__ ts, float* __restrict__ bo_f, float* __restrict__ bo_t,
    float* __restrict__ d0t)
{
  const float SC = 2.8853900817779268f;
  int i = blockIdx.x * 256 + threadIdx.x;
  if (i < 16512){
    int c = i % 129, h = i / 129;
    if (c == 0) bo_t[h] = b_out[i] * SC;
    else        bo_f[(size_t)(c-1)*128 + h] = b_out[i] * SC;
  }
  if (i < 1024) d0t[i] = ts[i*12 + 2] - ts[i*12 + 1];
}

// ---------- fused rows l=0,1 (f32 exact): F0, d0f[h][b] ----------
__global__ __launch_bounds__(256) void pose_fused(
    const float* __restrict__ fv, const float* __restrict__ fi,
    const float* __restrict__ w_red, const float* __restrict__ b_red,
    float* __restrict__ F0, float* __restrict__ d0f)
{
  __shared__ float pk[128][16];
  __shared__ float res[16][128];
  const int b0 = blockIdx.x * 8;
  const int t = threadIdx.x;
  const int h = t & 127, sg = t >> 7;
  float acc[8] = {0.f,0.f,0.f,0.f,0.f,0.f,0.f,0.f};
  for (int p = 0; p < 6; p++){
    __syncthreads();
    { const int s  = t >> 4;
      const int ch = (t & 15) * 8;
      const int b  = b0 + (s & 7);
      const int ll = s >> 3;
      const int kb = p*128 + ch;
      const float* src = (kb < 512) ? (fv + ((size_t)b*11 + ll)*512 + kb)
                                    : (fi + ((size_t)b*11 + ll)*256 + (kb - 512));
      float v[8];
      #pragma unroll
      for (int j = 0; j < 8; j++) v[j] = src[j];
      #pragma unroll
      for (int j = 0; j < 8; j++) pk[ch + j][s] = v[j];
    }
    __syncthreads();
    #pragma unroll 4
    for (int kk = 0; kk < 128; kk++){
      const float wv = w_red[(size_t)(p*128 + kk)*128 + h];
      f32x4 v0 = *(const f32x4*)&pk[kk][sg*8];
      f32x4 v1 = *(const f32x4*)&pk[kk][sg*8 + 4];
      acc[0] += v0.x*wv; acc[1] += v0.y*wv; acc[2] += v0.z*wv; acc[3] += v0.w*wv;
      acc[4] += v1.x*wv; acc[5] += v1.y*wv; acc[6] += v1.z*wv; acc[7] += v1.w*wv;
    }
  }
  __syncthreads();
  const float br = b_red[h];
  #pragma unroll
  for (int si = 0; si < 8; si++) res[sg*8 + si][h] = acc[si] + br;
  __syncthreads();
  if (sg == 0){
    #pragma unroll
    for (int si = 0; si < 8; si++){
      const int b = b0 + si;
      const float f0 = res[si][h];
      const float f1 = res[8 + si][h];
      F0[(size_t)b*128 + h] = f0;
      d0f[(size_t)h*1024 + b] = f1 - f0;
    }
  }
}

// zfrag byte address for (b, h) within buffer base
DEV uint32_t zaddr(int b, int h){
  return (uint32_t)(b >> 7)*32768u + (uint32_t)((b >> 4) & 7)*4096u + (uint32_t)(h >> 5)*1024u
       + ((uint32_t)(b & 15) + 16u*(((uint32_t)h & 31u) >> 3))*16u + ((uint32_t)h & 7u)*2u;
}

// ---------- z0 = x0 @ w_init + b_init (f32); zfrag[0]; S[b] ----------
__global__ __launch_bounds__(512) void pose_init(
    const float* __restrict__ F0, const float* __restrict__ ts,
    const float* __restrict__ w_init, const float* __restrict__ b_init,
    const float* __restrict__ d0f, const float* __restrict__ d0t,
    float* __restrict__ z_base, uint16_t* __restrict__ zfG,
    float* __restrict__ hT, float* __restrict__ S)
{
  __shared__ float Ft[128][64];
  const int b0 = blockIdx.x * 64;
  const int t = threadIdx.x;
  { const int b = t >> 3, ch = (t & 7)*16;
    #pragma unroll
    for (int j = 0; j < 16; j++) Ft[ch + j][b] = F0[(size_t)(b0 + b)*128 + ch + j];
  }
  __syncthreads();
  const int h = t & 127, rg = t >> 7;
  float acc[16];
  const float w0 = w_init[h], bi = b_init[h];
  #pragma unroll
  for (int r = 0; r < 16; r++){
    const int b = b0 + rg*16 + r;
    acc[r] = (ts[b*12 + 1] - ts[b*12 + 0]) * w0 + bi;
  }
  #pragma unroll 2
  for (int j = 0; j < 128; j++){
    const float wv = w_init[(j + 1)*128 + h];
    const float* pr = &Ft[j][rg*16];
    #pragma unroll
    for (int q = 0; q < 4; q++){
      f32x4 v = *(const f32x4*)(pr + q*4);
      acc[q*4+0] += v.x*wv; acc[q*4+1] += v.y*wv; acc[q*4+2] += v.z*wv; acc[q*4+3] += v.w*wv;
    }
  }
  #pragma unroll
  for (int r = 0; r < 16; r++){
    const int b = b0 + rg*16 + r;
    const float z = acc[r];
    z_base[(size_t)b*128 + h] = z;
    hT[(size_t)b*1280 + h] = z;
    *(uint16_t*)((char*)zfG + zaddr(b, h)) = f2bf(z);
  }
  if (t < 64){
    const int b = b0 + t;
    float s = d0t[b];
    for (int j = 0; j < 128; j++) s += d0f[(size_t)j*1024 + b];
    S[b] = s;
  }
}

// ---------- persistent: 144 evals; 1024 thr; 128-VGPR tier pinned via launch_bounds ----------
__global__ __launch_bounds__(1024, 4) void pose_persist(
    const uint16_t* __restrict__ Wg, const uint32_t* __restrict__ w1f,
    const uint32_t* __restrict__ w2f, const uint16_t* __restrict__ w0f,
    const float* __restrict__ b1, const float* __restrict__ b2,
    const float* __restrict__ bo_f, const float* __restrict__ bo_t,
    const float* __restrict__ d0f, const float* __restrict__ d0t,
    const float* __restrict__ Sv, const float* __restrict__ z_base,
    uint16_t* __restrict__ zfG, float* __restrict__ hT, uint32_t* __restrict__ bar)
{
  __shared__ __align__(16) char Lds[163840];    // 0..131071: W slice; 131072..: Hbuf (32 KB)
  const uint32_t HB = 131072u;
  const int t    = threadIdx.x;
  const int blk  = blockIdx.x;
  const int bt   = blk & 7;                     // b-team == XCD (32 blocks each)
  const int ht   = blk >> 3;                    // h-team (4 output h)
  const int w    = t >> 6, l = t & 63;
  const int l15  = l & 15, l4g = l >> 4;
  const int m8   = w & 7;                       // M-tile id within its role
  const int half = w >> 3;                      // col/M half (0/1)

  // ---- prologue: W slice -> LDS (once) ----
  { const i32x4* src = (const i32x4*)((const char*)Wg + (size_t)ht*131072);
    i32x4* dst = (i32x4*)Lds;
    #pragma unroll
    for (int i = 0; i < 8; i++) dst[t + 1024*i] = src[t + 1024*i];
  }

  // permanent per-lane state
  bf16x8 w1A[4];
  #pragma unroll
  for (int kb = 0; kb < 4; kb++)
    w1A[kb] = as_bf(*(const i32x4*)((const char*)w1f + (size_t)(m8*4 + kb)*1024 + l*16));

  float d0M[4][4];
  #pragma unroll
  for (int i = 0; i < 4; i++)
    #pragma unroll
    for (int nt = 0; nt < 4; nt++)
      d0M[i][nt] = d0f[(size_t)((m8*4 + i)*4 + l4g)*1024 + bt*128 + half*64 + nt*16 + l15];
  float d0c0[4];
  #pragma unroll
  for (int nt = 0; nt < 4; nt++)
    d0c0[nt] = (l4g == 0) ? d0t[bt*128 + half*64 + nt*16 + l15] : 0.f;

  // phase-B state: t<512 <-> (bl = t>>2 in team, h' = t&3)
  const int bl = t >> 2, hp = t & 3;
  const float HS = 0x1.999996p-6f;
  const float C2 = HS * 0.5f, C6 = HS / 6.f;
  float zb = 0.f, Sb = 0.f, av = 0.f;
  if (t < 512){
    zb = z_base[(size_t)(bt*128 + bl)*128 + ht*4 + hp];
    Sb = Sv[bt*128 + bl];
  }
  uint32_t* cnt = bar + bt*32;                  // per-team counter line
  const uint32_t zsl_off = (uint32_t)bt*32768u;
  __syncthreads();

  #pragma unroll 1
  for (int e = 0; e < 144; e++){
    // ---- stage z slice (32 KB) -> Hbuf, linear copy (sc1, once per block) ----
    { const char* zsrc = (const char*)zfG + (size_t)(e & 1)*262144 + zsl_off;
      #pragma unroll
      for (int i = 0; i < 2; i++){
        union { uint64_t q[2]; i32x4 v; } u;
        u.q[0] = ld_ic64(zsrc + t*16 + i*16384);
        u.q[1] = ld_ic64(zsrc + t*16 + i*16384 + 8);
        *(i32x4*)(Lds + HB + t*16 + i*16384) = u.v;
      }
    }
    __syncthreads();                            // Z: staged

    // ---- chain1 MFMA: z B-frags from LDS; results held in regs ----
    f32x4 acc1[4];
    #pragma unroll
    for (int nt2 = 0; nt2 < 4; nt2++){
      bf16x8 bz[4];
      #pragma unroll
      for (int kb = 0; kb < 4; kb++)
        bz[kb] = as_bf(*(const i32x4*)(Lds + HB + (uint32_t)(half*4 + nt2)*4096u + kb*1024 + l*16));
      f32x4 a = {0.f,0.f,0.f,0.f};
      #pragma unroll
      for (int kb = 0; kb < 4; kb++) a = MFMA(w1A[kb], bz[kb], a);
      acc1[nt2] = a;
    }
    __syncthreads();                            // A1: z fully consumed

    // ---- h1 = relu(acc1 + b1) -> Hbuf (overwrites z image) ----
    { const f32x4 b1v = *(const f32x4*)(b1 + m8*16 + l4g*4);
      #pragma unroll
      for (int nt2 = 0; nt2 < 4; nt2++){
        const int col = half*64 + nt2*16 + l15;
        const float r0 = fmaxf(acc1[nt2].x + b1v.x, 0.f);
        const float r1 = fmaxf(acc1[nt2].y + b1v.y, 0.f);
        const float r2 = fmaxf(acc1[nt2].z + b1v.z, 0.f);
        const float r3 = fmaxf(acc1[nt2].w + b1v.w, 0.f);
        i32x2 pv = { (int)pkbf(r0, r1), (int)pkbf(r2, r3) };
        *(i32x2*)(Lds + HB + aoff((uint32_t)col, (uint32_t)(m8*16 + l4g*4)*2)) = pv;
      }
    }
    __syncthreads();                            // A2: h1 ready

    // ---- chain2: h2 = relu(w2 . h1); wave (col-tile m8, M-half) ----
    bf16x8 bh1[4];
    #pragma unroll
    for (int kb = 0; kb < 4; kb++)
      bh1[kb] = as_bf(*(const i32x4*)(Lds + HB + aoff((uint32_t)(m8*16 + l15), kb*64 + l4g*16)));
    __syncthreads();                            // B: all bh1 reads done before overwrite
    #pragma unroll
    for (int i = 0; i < 4; i++){
      const int Mt = half*4 + i;
      bf16x8 a2[4];
      #pragma unroll
      for (int kb = 0; kb < 4; kb++)
        a2[kb] = as_bf(*(const i32x4*)((const char*)w2f + (size_t)(Mt*4 + kb)*1024 + l*16));
      f32x4 acc = {0.f,0.f,0.f,0.f};
      #pragma unroll
      for (int kb = 0; kb < 4; kb++) acc = MFMA(a2[kb], bh1[kb], acc);
      const f32x4 b2v = *(const f32x4*)(b2 + Mt*16 + l4g*4);
      const float r0 = fmaxf(acc.x + b2v.x, 0.f);
      const float r1 = fmaxf(acc.y + b2v.y, 0.f);
      const float r2 = fmaxf(acc.z + b2v.z, 0.f);
      const float r3 = fmaxf(acc.w + b2v.w, 0.f);
      i32x2 pv = { (int)pkbf(r0, r1), (int)pkbf(r2, r3) };
      *(i32x2*)(Lds + HB + aoff((uint32_t)(m8*16 + l15), (uint32_t)(Mt*16 + l4g*4)*2)) = pv;
    }
    __syncthreads();                            // C: h2 ready

    // ---- big GEMM: wave (mw=m8: 4 M-tiles, nw=half: 64 b) in 2 N-passes ----
    f32x4 oacc[4];
    const f32x4 Z4 = {0.f,0.f,0.f,0.f};
    #pragma unroll
    for (int nt = 0; nt < 4; nt++) oacc[nt] = Z4;

    #pragma unroll
    for (int p = 0; p < 2; p++){
      bf16x8 bh2[2][4];
      #pragma unroll
      for (int n2 = 0; n2 < 2; n2++)
        #pragma unroll
        for (int kb = 0; kb < 4; kb++)
          bh2[n2][kb] = as_bf(*(const i32x4*)(Lds + HB +
              aoff((uint32_t)(half*64 + (p*2 + n2)*16 + l15), kb*64 + l4g*16)));
      #pragma unroll
      for (int i = 0; i < 4; i++){
        const int Mt = m8*4 + i;
        bf16x8 A[4];
        #pragma unroll
        for (int kb = 0; kb < 4; kb++)
          A[kb] = as_bf(*(const i32x4*)(Lds + aoff((uint32_t)(Mt*16 + l15), kb*64 + l4g*16)));
        const f32x4 bo4 = *(const f32x4*)(bo_f + (size_t)(Mt*4 + l4g)*128 + ht*4);
        #pragma unroll
        for (int n2 = 0; n2 < 2; n2++){
          f32x4 acc = {0.f,0.f,0.f,0.f};
          #pragma unroll
          for (int kb = 0; kb < 4; kb++) acc = MFMA(A[kb], bh2[n2][kb], acc);
          f32x4 rr;
          rr.x = __builtin_amdgcn_rcpf(__builtin_amdgcn_exp2f(acc.x + bo4.x) + 1.f);
          rr.y = __builtin_amdgcn_rcpf(__builtin_amdgcn_exp2f(acc.y + bo4.y) + 1.f);
          rr.z = __builtin_amdgcn_rcpf(__builtin_amdgcn_exp2f(acc.z + bo4.z) + 1.f);
          rr.w = __builtin_amdgcn_rcpf(__builtin_amdgcn_exp2f(acc.w + bo4.w) + 1.f);
          oacc[p*2 + n2] += rr * d0M[i][p*2 + n2];
        }
      }
      if (m8 == 0){   // c=0 (time) channel tile
        bf16x8 A0[4];
        #pragma unroll
        for (int kb = 0; kb < 4; kb++)
          A0[kb] = as_bf(*(const i32x4*)((const char*)w0f + (size_t)ht*4096 + kb*1024 + l*16));
        const f32x4 bt4 = *(const f32x4*)(bo_t + ht*4);
        #pragma unroll
        for (int n2 = 0; n2 < 2; n2++){
          f32x4 acc = {0.f,0.f,0.f,0.f};
          #pragma unroll
          for (int kb = 0; kb < 4; kb++) acc = MFMA(A0[kb], bh2[n2][kb], acc);
          f32x4 rr;
          rr.x = __builtin_amdgcn_rcpf(__builtin_amdgcn_exp2f(acc.x + bt4.x) + 1.f);
          rr.y = __builtin_amdgcn_rcpf(__builtin_amdgcn_exp2f(acc.y + bt4.y) + 1.f);
          rr.z = __builtin_amdgcn_rcpf(__builtin_amdgcn_exp2f(acc.z + bt4.z) + 1.f);
          rr.w = __builtin_amdgcn_rcpf(__builtin_amdgcn_exp2f(acc.w + bt4.w) + 1.f);
          oacc[p*2 + n2] += rr * d0c0[p*2 + n2];
        }
      }
    }

    // in-wave reduce over l4g groups
    #pragma unroll
    for (int nt = 0; nt < 4; nt++){
      #pragma unroll
      for (int c = 0; c < 4; c++){
        float v = oacc[nt][c];
        v += __shfl_xor(v, 16, 64);
        v += __shfl_xor(v, 32, 64);
        oacc[nt][c] = v;
      }
    }
    __syncthreads();                            // D: all h2 reads done before overwrite
    if (l < 16){
      #pragma unroll
      for (int nt = 0; nt < 4; nt++){
        const int b = half*64 + nt*16 + l15;
        *(f32x4*)(Lds + HB + m8*2048 + b*16) = oacc[nt];
      }
    }
    __syncthreads();                            // E: partials ready

    // ---- phase B: block-local reduce + RK4 (t<512) ----
    if (t < 512){
      float psum = 0.f;
      #pragma unroll
      for (int m = 0; m < 8; m++)
        psum += *(const float*)(Lds + HB + m*2048 + bl*16 + hp*4);
      const float kk = Sb - 2.f*psum;
      const int st = e & 3;
      float ze;
      if (st == 0){      av = kk;        ze = zb + C2*kk; }
      else if (st == 1){ av += 2.f*kk;   ze = zb + C2*kk; }
      else if (st == 2){ av += 2.f*kk;   ze = zb + HS*kk; }
      else {
        zb += C6*(av + kk); ze = zb;
        if ((e & 15) == 15)
          hT[(size_t)(bt*128 + bl)*1280 + (size_t)((e >> 4) + 1)*128 + ht*4 + hp] = zb;
      }
      *(uint16_t*)(Lds + HB + 16384 + t*2) = f2bf(ze);
    }
    __syncthreads();                            // F: zpack ready

    if (e < 143){
      // ---- publish zfrag[(e+1)&1] slice (128 B/block, XCD-local) ----
      if (t < 128){
        uint64_t zw = *(const uint64_t*)(Lds + HB + 16384 + t*8);
        char* zdst = (char*)zfG + (size_t)((e + 1) & 1)*262144 + zsl_off
                   + (t >> 4)*4096 + (ht >> 3)*1024
                   + ((t & 15) + 16*((ht & 7) >> 1))*16 + (ht & 1)*8;
        st_ic64(zdst, zw);
      }
      __syncthreads();                          // G: drain publish stores
      if (t == 0){
        __hip_atomic_fetch_add(cnt, 1u, __ATOMIC_RELAXED, __HIP_MEMORY_SCOPE_AGENT);
        int spins = 0;
        while (__hip_atomic_load(cnt, __ATOMIC_RELAXED, __HIP_MEMORY_SCOPE_AGENT) < 32u*(uint32_t)(e + 1)){
          __builtin_amdgcn_s_sleep(1);
          if (++spins > (1 << 20)) break;       // safety escape, not a hang
        }
        asm volatile("" ::: "memory");
      }
      __syncthreads();                          // H: team released
    }
  }
}

// ---------- readout ----------
__global__ __launch_bounds__(256) void pose_readout(
    const float* __restrict__ hT, const float* __restrict__ w_r1, const float* __restrict__ b_r1,
    const float* __restrict__ w_r2, const float* __restrict__ b_r2,
    float* __restrict__ out_poses, float* __restrict__ out_z)
{
  if (blockIdx.x >= 320){
    const int cb = blockIdx.x - 320;
    const int base = cb*2048 + threadIdx.x*4;
    #pragma unroll
    for (int p = 0; p < 2; p++){
      const int i = base + p*1024;
      const int b = i >> 7, h = i & 127;
      *(f32x4*)(out_z + i) = *(const f32x4*)(hT + (size_t)b*1280 + 1152 + h);
    }
    return;
  }
  __shared__ float htl[128][32];
  __shared__ float al[32][128];
  const int r0 = blockIdx.x * 32;
  const int t = threadIdx.x;
  { const int row = t >> 3, ch = (t & 7)*16;
    #pragma unroll
    for (int j = 0; j < 16; j++)
      htl[ch + j][row] = hT[(size_t)(r0 + row)*128 + ch + j];
  }
  __syncthreads();
  const int j = t & 127, rg = t >> 7;
  float a[16];
  const float bj = b_r1[j];
  #pragma unroll
  for (int r = 0; r < 16; r++) a[r] = bj;
  #pragma unroll 2
  for (int kk = 0; kk < 128; kk++){
    const float wv = w_r1[(size_t)kk*128 + j];
    const float* pr = &htl[kk][rg*16];
    #pragma unroll
    for (int q = 0; q < 4; q++){
      f32x4 v = *(const f32x4*)(pr + q*4);
      a[q*4+0] += v.x*wv; a[q*4+1] += v.y*wv; a[q*4+2] += v.z*wv; a[q*4+3] += v.w*wv;
    }
  }
  #pragma unroll
  for (int r = 0; r < 16; r++){
    float v = a[r];
    al[rg*16 + r][j] = (v > 0.f) ? v : 0.1f*v;
  }
  __syncthreads();
  if (t < 192){
    const int row = t / 6, p = t % 6;
    float s = b_r2[p];
    const float* ar = al[row];
    #pragma unroll 4
    for (int jj = 0; jj < 128; jj++) s += ar[jj] * w_r2[jj*6 + p];
    out_poses[(size_t)(r0 + row)*6 + p] = s;
  }
}

// ---------- host ----------
extern "C" void kernel_launch(void* const* d_in, const int* in_sizes, int n_in,
                              void* d_out, int out_size, void* d_ws, size_t ws_size,
                              hipStream_t stream)
{
  (void)in_sizes; (void)n_in; (void)out_size; (void)ws_size;
  const float* fv    = (const float*)d_in[0];
  const float* fi    = (const float*)d_in[1];
  const float* ts    = (const float*)d_in[2];
  const float* w_red = (const float*)d_in[3];
  const float* b_red = (const float*)d_in[4];
  const float* w_init= (const float*)d_in[5];
  const float* b_init= (const float*)d_in[6];
  const float* w_h1  = (const float*)d_in[7];
  const float* b_h1  = (const float*)d_in[8];
  const float* w_h2  = (const float*)d_in[9];
  const float* b_h2  = (const float*)d_in[10];
  const float* w_out = (const float*)d_in[11];
  const float* b_out = (const float*)d_in[12];
  const float* w_r1  = (const float*)d_in[13];
  const float* b_r1  = (const float*)d_in[14];
  const float* w_r2  = (const float*)d_in[15];
  const float* b_r2  = (const float*)d_in[16];

  char* p = (char*)d_ws;
  auto take = [&](size_t n){ char* r = p; p += (n + 255) & ~(size_t)255; return r; };
  uint32_t* bar   = (uint32_t*)take(4096);
  uint16_t* Wg    = (uint16_t*)take((size_t)32*131072);   // per-ht LDS images (4MB)
  uint16_t* w0f   = (uint16_t*)take((size_t)32*4096);     // c0-tile A-frags per ht
  uint32_t* w1f   = (uint32_t*)take(32768);               // chain A-frags
  uint32_t* w2f   = (uint32_t*)take(32768);
  float* bo_f     = (float*)take((size_t)128*128*4);
  float* bo_t     = (float*)take(128*4);
  float* d0f      = (float*)take((size_t)128*1024*4);     // [c'][b]
  float* d0t      = (float*)take(1024*4);
  float* Sv       = (float*)take(1024*4);
  float* F0       = (float*)take((size_t)1024*128*4);
  float* z_base   = (float*)take((size_t)1024*128*4);
  uint16_t* zfG   = (uint16_t*)take((size_t)2*262144);    // ping-pong zfrag
  float* hT       = (float*)take((size_t)1024*10*128*4);

  float* out_poses = (float*)d_out;
  float* out_z     = (float*)d_out + 61440;

  hipMemsetAsync(bar, 0, 4096, stream);
  hipMemsetAsync(w0f, 0, (size_t)32*4096*2, stream);
  pose_convW<<<260, 256, 0, stream>>>(w_out, Wg, w0f);
  pose_convC<<<2,   256, 0, stream>>>(w_h1, w_h2, w1f, w2f);
  pose_misc <<<65,  256, 0, stream>>>(b_out, ts, bo_f, bo_t, d0t);
  pose_fused<<<128, 256, 0, stream>>>(fv, fi, w_red, b_red, F0, d0f);
  pose_init <<<16,  512, 0, stream>>>(F0, ts, w_init, b_init, d0f, d0t, z_base, zfG, hT, Sv);

  pose_persist<<<256, 1024, 0, stream>>>(Wg, w1f, w2f, w0f, b_h1, b_h2, bo_f, bo_t,
                                         d0f, d0t, Sv, z_base, zfG, hT, bar);

  pose_readout<<<384, 256, 0, stream>>>(hT, w_r1, b_r1, w_r2, b_r2, out_poses, out_z);
}

// Round 9
// 4143.864 us; speedup vs baseline: 1.2329x; 1.2329x over previous
//
#include <hip/hip_runtime.h>
#include <stdint.h>

typedef float   f32x4 __attribute__((ext_vector_type(4)));
typedef float   f32x2 __attribute__((ext_vector_type(2)));
typedef int     i32x4 __attribute__((ext_vector_type(4)));
typedef int     i32x2 __attribute__((ext_vector_type(2)));
typedef __bf16  bf16x8 __attribute__((ext_vector_type(8)));

#define DEV __device__ __forceinline__

// ---------- helpers ----------
DEV uint16_t f2bf(float f){                       // RNE f32->bf16
  uint32_t u = __float_as_uint(f);
  u += 0x7fffu + ((u >> 16) & 1u);
  return (uint16_t)(u >> 16);
}
DEV uint32_t pkbf(float lo, float hi){            // pack 2 bf16 into u32
  uint32_t r;
  asm("v_cvt_pk_bf16_f32 %0, %1, %2" : "=v"(r) : "v"(lo), "v"(hi));
  return r;
}
// byte offset inside a [row][128 bf16] (256B) row with XOR-16B bank swizzle
DEV uint32_t aoff(uint32_t row, uint32_t q){ return (row << 8) + (q ^ ((row & 7u) << 4)); }

DEV f32x4 MFMA(bf16x8 a, bf16x8 b, f32x4 c){
  return __builtin_amdgcn_mfma_f32_16x16x32_bf16(a, b, c, 0, 0, 0);
}
DEV bf16x8 as_bf(i32x4 v){ union { i32x4 i; bf16x8 b; } u; u.i = v; return u.b; }

DEV uint64_t ld_ic64(const void* p){
  return __hip_atomic_load((const uint64_t*)p, __ATOMIC_RELAXED, __HIP_MEMORY_SCOPE_AGENT);
}
DEV void st_ic64(void* p, uint64_t v){
  __hip_atomic_store((uint64_t*)p, v, __ATOMIC_RELAXED, __HIP_MEMORY_SCOPE_AGENT);
}

// ---------- W_out -> per-ht LDS images (Wg) + c0-tile frags (w0f), scaled ----------
// src [128 k][16512 n], n = h*129 + c. c>=1: row r=(c-1)*4+(h&3), image ht=h>>2.
__global__ __launch_bounds__(256) void pose_convW(const float* __restrict__ src,
    uint16_t* __restrict__ Wg, uint16_t* __restrict__ w0f)
{
  __shared__ float tile[32][256];
  const float SC = 2.8853900817779268f;   // 2*log2(e)
  int bk = blockIdx.x & 3, bn = blockIdx.x >> 2;
  int k0 = bk * 32, n0 = bn * 256;
  int t = threadIdx.x;
  for (int r = 0; r < 32; r++){
    int n = n0 + t;
    tile[r][t] = (n < 16512) ? src[(size_t)(k0 + r) * 16512 + n] : 0.f;
  }
  __syncthreads();
  int n = n0 + t;
  if (n < 16512){
    int c = n % 129, hfull = n / 129;
    int ht = hfull >> 2;
    #pragma unroll
    for (int o = 0; o < 4; o++){
      uint32_t w0 = (uint32_t)f2bf(tile[o*8+0][t]*SC) | ((uint32_t)f2bf(tile[o*8+1][t]*SC) << 16);
      uint32_t w1 = (uint32_t)f2bf(tile[o*8+2][t]*SC) | ((uint32_t)f2bf(tile[o*8+3][t]*SC) << 16);
      uint32_t w2 = (uint32_t)f2bf(tile[o*8+4][t]*SC) | ((uint32_t)f2bf(tile[o*8+5][t]*SC) << 16);
      uint32_t w3 = (uint32_t)f2bf(tile[o*8+6][t]*SC) | ((uint32_t)f2bf(tile[o*8+7][t]*SC) << 16);
      i32x4 val = { (int)w0, (int)w1, (int)w2, (int)w3 };
      uint32_t kg = (uint32_t)(k0 + o*8);
      if (c > 0){
        uint32_t r = (uint32_t)(c - 1)*4 + (hfull & 3);
        uint32_t byte = (uint32_t)ht*131072u + r*256u + ((kg*2u) ^ ((r & 7u) << 4));
        *(i32x4*)((char*)Wg + byte) = val;
      } else {
        uint32_t r0 = (uint32_t)(hfull & 3);
        uint32_t byte = (uint32_t)ht*4096u + (kg >> 5)*1024u + (r0 + 16u*((kg >> 3) & 3u))*16u;
        *(i32x4*)((char*)w0f + byte) = val;
      }
    }
  }
}

// ---------- chain weights -> A-frag layout: dst[Mt 8][kb 4][l 64][j 8] ----------
__global__ __launch_bounds__(256) void pose_convC(const float* __restrict__ w_h1,
    const float* __restrict__ w_h2, uint32_t* __restrict__ w1f, uint32_t* __restrict__ w2f)
{
  const float* src = blockIdx.x ? w_h2 : w_h1;
  uint32_t* dst = blockIdx.x ? w2f : w1f;
  int t = threadIdx.x;
  for (int ii = 0; ii < 32; ii++){
    int u = t*32 + ii;
    int p = u & 3, l = (u >> 2) & 63, kb = (u >> 8) & 3, Mt = u >> 10;
    int k = kb*32 + (l >> 4)*8 + 2*p;
    int n = Mt*16 + (l & 15);
    uint32_t v = (uint32_t)f2bf(src[(size_t)k*128 + n]) |
                 ((uint32_t)f2bf(src[(size_t)(k+1)*128 + n]) << 16);
    dst[u] = v;
  }
}

// ---------- bo_f[c'][h], bo_t[h], d0t[b] ----------
__global__ __launch_bounds__(256) void pose_misc(const float* __restrict__ b_out,
    const float* __restrict__ ts, float* __restrict__ bo_f, float* __restrict__ bo_t,
    float* __restrict__ d0t)
{
  const float SC = 2.8853900817779268f;
  int i = blockIdx.x * 256 + threadIdx.x;
  if (i < 16512){
    int c = i % 129, h = i / 129;
    if (c == 0) bo_t[h] = b_out[i] * SC;
    else        bo_f[(size_t)(c-1)*128 + h] = b_out[i] * SC;
  }
  if (i < 1024) d0t[i] = ts[i*12 + 2] - ts[i*12 + 1];
}

// ---------- fused rows l=0,1 (f32 exact): F0, d0f[h][b] ----------
__global__ __launch_bounds__(256) void pose_fused(
    const float* __restrict__ fv, const float* __restrict__ fi,
    const float* __restrict__ w_red, const float* __restrict__ b_red,
    float* __restrict__ F0, float* __restrict__ d0f)
{
  __shared__ float pk[128][16];
  __shared__ float res[16][128];
  const int b0 = blockIdx.x * 8;
  const int t = threadIdx.x;
  const int h = t & 127, sg = t >> 7;
  float acc[8] = {0.f,0.f,0.f,0.f,0.f,0.f,0.f,0.f};
  for (int p = 0; p < 6; p++){
    __syncthreads();
    { const int s  = t >> 4;
      const int ch = (t & 15) * 8;
      const int b  = b0 + (s & 7);
      const int ll = s >> 3;
      const int kb = p*128 + ch;
      const float* src = (kb < 512) ? (fv + ((size_t)b*11 + ll)*512 + kb)
                                    : (fi + ((size_t)b*11 + ll)*256 + (kb - 512));
      float v[8];
      #pragma unroll
      for (int j = 0; j < 8; j++) v[j] = src[j];
      #pragma unroll
      for (int j = 0; j < 8; j++) pk[ch + j][s] = v[j];
    }
    __syncthreads();
    #pragma unroll 4
    for (int kk = 0; kk < 128; kk++){
      const float wv = w_red[(size_t)(p*128 + kk)*128 + h];
      f32x4 v0 = *(const f32x4*)&pk[kk][sg*8];
      f32x4 v1 = *(const f32x4*)&pk[kk][sg*8 + 4];
      acc[0] += v0.x*wv; acc[1] += v0.y*wv; acc[2] += v0.z*wv; acc[3] += v0.w*wv;
      acc[4] += v1.x*wv; acc[5] += v1.y*wv; acc[6] += v1.z*wv; acc[7] += v1.w*wv;
    }
  }
  __syncthreads();
  const float br = b_red[h];
  #pragma unroll
  for (int si = 0; si < 8; si++) res[sg*8 + si][h] = acc[si] + br;
  __syncthreads();
  if (sg == 0){
    #pragma unroll
    for (int si = 0; si < 8; si++){
      const int b = b0 + si;
      const float f0 = res[si][h];
      const float f1 = res[8 + si][h];
      F0[(size_t)b*128 + h] = f0;
      d0f[(size_t)h*1024 + b] = f1 - f0;
    }
  }
}

// zfrag byte address for (b, h) within buffer base
DEV uint32_t zaddr(int b, int h){
  return (uint32_t)(b >> 7)*32768u + (uint32_t)((b >> 4) & 7)*4096u + (uint32_t)(h >> 5)*1024u
       + ((uint32_t)(b & 15) + 16u*(((uint32_t)h & 31u) >> 3))*16u + ((uint32_t)h & 7u)*2u;
}

// ---------- z0 = x0 @ w_init + b_init (f32); zfrag[0]; S[b] ----------
__global__ __launch_bounds__(512) void pose_init(
    const float* __restrict__ F0, const float* __restrict__ ts,
    const float* __restrict__ w_init, const float* __restrict__ b_init,
    const float* __restrict__ d0f, const float* __restrict__ d0t,
    float* __restrict__ z_base, uint16_t* __restrict__ zfG,
    float* __restrict__ hT, float* __restrict__ S)
{
  __shared__ float Ft[128][64];
  const int b0 = blockIdx.x * 64;
  const int t = threadIdx.x;
  { const int b = t >> 3, ch = (t & 7)*16;
    #pragma unroll
    for (int j = 0; j < 16; j++) Ft[ch + j][b] = F0[(size_t)(b0 + b)*128 + ch + j];
  }
  __syncthreads();
  const int h = t & 127, rg = t >> 7;
  float acc[16];
  const float w0 = w_init[h], bi = b_init[h];
  #pragma unroll
  for (int r = 0; r < 16; r++){
    const int b = b0 + rg*16 + r;
    acc[r] = (ts[b*12 + 1] - ts[b*12 + 0]) * w0 + bi;
  }
  #pragma unroll 2
  for (int j = 0; j < 128; j++){
    const float wv = w_init[(j + 1)*128 + h];
    const float* pr = &Ft[j][rg*16];
    #pragma unroll
    for (int q = 0; q < 4; q++){
      f32x4 v = *(const f32x4*)(pr + q*4);
      acc[q*4+0] += v.x*wv; acc[q*4+1] += v.y*wv; acc[q*4+2] += v.z*wv; acc[q*4+3] += v.w*wv;
    }
  }
  #pragma unroll
  for (int r = 0; r < 16; r++){
    const int b = b0 + rg*16 + r;
    const float z = acc[r];
    z_base[(size_t)b*128 + h] = z;
    hT[(size_t)b*1280 + h] = z;
    *(uint16_t*)((char*)zfG + zaddr(b, h)) = f2bf(z);
  }
  if (t < 64){
    const int b = b0 + t;
    float s = d0t[b];
    for (int j = 0; j < 128; j++) s += d0f[(size_t)j*1024 + b];
    S[b] = s;
  }
}

// ---------- persistent: 144 evals; 1024 thr; min-1-block bound; low per-thread state ----------
__global__ __launch_bounds__(1024, 1) void pose_persist(
    const uint16_t* __restrict__ Wg, const uint32_t* __restrict__ w1f,
    const uint32_t* __restrict__ w2f, const uint16_t* __restrict__ w0f,
    const float* __restrict__ b1, const float* __restrict__ b2,
    const float* __restrict__ bo_f, const float* __restrict__ bo_t,
    const float* __restrict__ d0f, const float* __restrict__ d0t,
    const float* __restrict__ Sv, const float* __restrict__ z_base,
    uint16_t* __restrict__ zfG, float* __restrict__ hT, uint32_t* __restrict__ bar)
{
  __shared__ __align__(16) char Lds[163840];    // 0..131071: W slice; 131072..: Hbuf (32 KB)
  const uint32_t HB = 131072u;
  const int t    = threadIdx.x;
  const int blk  = blockIdx.x;
  const int bt   = blk & 7;                     // b-team == XCD (32 blocks each)
  const int ht   = blk >> 3;                    // h-team (4 output h)
  const int w    = t >> 6, l = t & 63;
  const int l15  = l & 15, l4g = l >> 4;
  const int m8   = w & 7;                       // M-tile id within its role
  const int half = w >> 3;                      // col/M half (0/1)

  // ---- prologue: W slice -> LDS (once) ----
  { const i32x4* src = (const i32x4*)((const char*)Wg + (size_t)ht*131072);
    i32x4* dst = (i32x4*)Lds;
    #pragma unroll
    for (int i = 0; i < 8; i++) dst[t + 1024*i] = src[t + 1024*i];
  }

  // L1-resident per-use tables (NOT kernel-lifetime registers):
  const float* d0p  = d0f + (size_t)(m8*16 + l4g)*1024 + bt*128 + half*64 + l15; // d0p[i*4096 + n*16]
  const float* d0tp = d0t + bt*128 + half*64 + l15;                              // d0tp[n*16]

  // phase-B state: t<512 <-> (bl = t>>2 in team, h' = t&3)
  const int bl = t >> 2, hp = t & 3;
  const float HS = 0x1.999996p-6f;
  const float C2 = HS * 0.5f, C6 = HS / 6.f;
  float zb = 0.f, Sb = 0.f, av = 0.f;
  if (t < 512){
    zb = z_base[(size_t)(bt*128 + bl)*128 + ht*4 + hp];
    Sb = Sv[bt*128 + bl];
  }
  uint32_t* cnt = bar + bt*32;                  // per-team counter line
  const uint32_t zsl_off = (uint32_t)bt*32768u;
  __syncthreads();

  #pragma unroll 1
  for (int e = 0; e < 144; e++){
    // ---- stage z slice (32 KB) -> Hbuf, linear copy (agent loads, once per block) ----
    { const char* zsrc = (const char*)zfG + (size_t)(e & 1)*262144 + zsl_off;
      #pragma unroll
      for (int i = 0; i < 2; i++){
        union { uint64_t q[2]; i32x4 v; } u;
        u.q[0] = ld_ic64(zsrc + t*16 + i*16384);
        u.q[1] = ld_ic64(zsrc + t*16 + i*16384 + 8);
        *(i32x4*)(Lds + HB + t*16 + i*16384) = u.v;
      }
    }
    __syncthreads();                            // Z: staged

    // ---- chain1 MFMA: w1 A-frags loaded per eval (L1-hit), z B-frags from LDS ----
    f32x4 acc1[4];
    { bf16x8 w1A[4];                            // short-lived: dies before big GEMM
      #pragma unroll
      for (int kb = 0; kb < 4; kb++)
        w1A[kb] = as_bf(*(const i32x4*)((const char*)w1f + (size_t)(m8*4 + kb)*1024 + l*16));
      #pragma unroll
      for (int nt2 = 0; nt2 < 4; nt2++){
        bf16x8 bz[4];
        #pragma unroll
        for (int kb = 0; kb < 4; kb++)
          bz[kb] = as_bf(*(const i32x4*)(Lds + HB + (uint32_t)(half*4 + nt2)*4096u + kb*1024 + l*16));
        f32x4 a = {0.f,0.f,0.f,0.f};
        #pragma unroll
        for (int kb = 0; kb < 4; kb++) a = MFMA(w1A[kb], bz[kb], a);
        acc1[nt2] = a;
      }
    }
    __syncthreads();                            // A1: z fully consumed

    // ---- h1 = relu(acc1 + b1) -> Hbuf (overwrites z image) ----
    { const f32x4 b1v = *(const f32x4*)(b1 + m8*16 + l4g*4);
      #pragma unroll
      for (int nt2 = 0; nt2 < 4; nt2++){
        const int col = half*64 + nt2*16 + l15;
        const float r0 = fmaxf(acc1[nt2].x + b1v.x, 0.f);
        const float r1 = fmaxf(acc1[nt2].y + b1v.y, 0.f);
        const float r2 = fmaxf(acc1[nt2].z + b1v.z, 0.f);
        const float r3 = fmaxf(acc1[nt2].w + b1v.w, 0.f);
        i32x2 pv = { (int)pkbf(r0, r1), (int)pkbf(r2, r3) };
        *(i32x2*)(Lds + HB + aoff((uint32_t)col, (uint32_t)(m8*16 + l4g*4)*2)) = pv;
      }
    }
    __syncthreads();                            // A2: h1 ready

    // ---- chain2: h2 = relu(w2 . h1); wave (col-tile m8, M-half) ----
    bf16x8 bh1[4];
    #pragma unroll
    for (int kb = 0; kb < 4; kb++)
      bh1[kb] = as_bf(*(const i32x4*)(Lds + HB + aoff((uint32_t)(m8*16 + l15), kb*64 + l4g*16)));
    __syncthreads();                            // B: all bh1 reads done before overwrite
    #pragma unroll
    for (int i = 0; i < 4; i++){
      const int Mt = half*4 + i;
      bf16x8 a2[4];
      #pragma unroll
      for (int kb = 0; kb < 4; kb++)
        a2[kb] = as_bf(*(const i32x4*)((const char*)w2f + (size_t)(Mt*4 + kb)*1024 + l*16));
      f32x4 acc = {0.f,0.f,0.f,0.f};
      #pragma unroll
      for (int kb = 0; kb < 4; kb++) acc = MFMA(a2[kb], bh1[kb], acc);
      const f32x4 b2v = *(const f32x4*)(b2 + Mt*16 + l4g*4);
      const float r0 = fmaxf(acc.x + b2v.x, 0.f);
      const float r1 = fmaxf(acc.y + b2v.y, 0.f);
      const float r2 = fmaxf(acc.z + b2v.z, 0.f);
      const float r3 = fmaxf(acc.w + b2v.w, 0.f);
      i32x2 pv = { (int)pkbf(r0, r1), (int)pkbf(r2, r3) };
      *(i32x2*)(Lds + HB + aoff((uint32_t)(m8*16 + l15), (uint32_t)(Mt*16 + l4g*4)*2)) = pv;
    }
    __syncthreads();                            // C: h2 ready

    // ---- big GEMM: wave (mw=m8: 4 M-tiles, nw=half: 64 b) in 2 N-passes ----
    f32x4 oacc[4];
    const f32x4 Z4 = {0.f,0.f,0.f,0.f};
    #pragma unroll
    for (int nt = 0; nt < 4; nt++) oacc[nt] = Z4;

    #pragma unroll
    for (int p = 0; p < 2; p++){
      bf16x8 bh2[2][4];
      #pragma unroll
      for (int n2 = 0; n2 < 2; n2++)
        #pragma unroll
        for (int kb = 0; kb < 4; kb++)
          bh2[n2][kb] = as_bf(*(const i32x4*)(Lds + HB +
              aoff((uint32_t)(half*64 + (p*2 + n2)*16 + l15), kb*64 + l4g*16)));
      #pragma unroll
      for (int i = 0; i < 4; i++){
        const int Mt = m8*4 + i;
        bf16x8 A[4];
        #pragma unroll
        for (int kb = 0; kb < 4; kb++)
          A[kb] = as_bf(*(const i32x4*)(Lds + aoff((uint32_t)(Mt*16 + l15), kb*64 + l4g*16)));
        const f32x4 bo4 = *(const f32x4*)(bo_f + (size_t)(Mt*4 + l4g)*128 + ht*4);
        #pragma unroll
        for (int n2 = 0; n2 < 2; n2++){
          f32x4 acc = {0.f,0.f,0.f,0.f};
          #pragma unroll
          for (int kb = 0; kb < 4; kb++) acc = MFMA(A[kb], bh2[n2][kb], acc);
          f32x4 rr;
          rr.x = __builtin_amdgcn_rcpf(__builtin_amdgcn_exp2f(acc.x + bo4.x) + 1.f);
          rr.y = __builtin_amdgcn_rcpf(__builtin_amdgcn_exp2f(acc.y + bo4.y) + 1.f);
          rr.z = __builtin_amdgcn_rcpf(__builtin_amdgcn_exp2f(acc.z + bo4.z) + 1.f);
          rr.w = __builtin_amdgcn_rcpf(__builtin_amdgcn_exp2f(acc.w + bo4.w) + 1.f);
          oacc[p*2 + n2] += rr * d0p[(size_t)i*4096 + (p*2 + n2)*16];
        }
      }
      if (m8 == 0){   // c=0 (time) channel tile
        bf16x8 A0[4];
        #pragma unroll
        for (int kb = 0; kb < 4; kb++)
          A0[kb] = as_bf(*(const i32x4*)((const char*)w0f + (size_t)ht*4096 + kb*1024 + l*16));
        const f32x4 bt4 = *(const f32x4*)(bo_t + ht*4);
        #pragma unroll
        for (int n2 = 0; n2 < 2; n2++){
          f32x4 acc = {0.f,0.f,0.f,0.f};
          #pragma unroll
          for (int kb = 0; kb < 4; kb++) acc = MFMA(A0[kb], bh2[n2][kb], acc);
          f32x4 rr;
          rr.x = __builtin_amdgcn_rcpf(__builtin_amdgcn_exp2f(acc.x + bt4.x) + 1.f);
          rr.y = __builtin_amdgcn_rcpf(__builtin_amdgcn_exp2f(acc.y + bt4.y) + 1.f);
          rr.z = __builtin_amdgcn_rcpf(__builtin_amdgcn_exp2f(acc.z + bt4.z) + 1.f);
          rr.w = __builtin_amdgcn_rcpf(__builtin_amdgcn_exp2f(acc.w + bt4.w) + 1.f);
          const float dc = (l4g == 0) ? d0tp[(p*2 + n2)*16] : 0.f;
          oacc[p*2 + n2] += rr * dc;
        }
      }
    }

    // in-wave reduce over l4g groups
    #pragma unroll
    for (int nt = 0; nt < 4; nt++){
      #pragma unroll
      for (int c = 0; c < 4; c++){
        float v = oacc[nt][c];
        v += __shfl_xor(v, 16, 64);
        v += __shfl_xor(v, 32, 64);
        oacc[nt][c] = v;
      }
    }
    __syncthreads();                            // D: all h2 reads done before overwrite
    if (l < 16){
      #pragma unroll
      for (int nt = 0; nt < 4; nt++){
        const int b = half*64 + nt*16 + l15;
        *(f32x4*)(Lds + HB + m8*2048 + b*16) = oacc[nt];
      }
    }
    __syncthreads();                            // E: partials ready

    // ---- phase B: block-local reduce + RK4 (t<512) ----
    if (t < 512){
      float psum = 0.f;
      #pragma unroll
      for (int m = 0; m < 8; m++)
        psum += *(const float*)(Lds + HB + m*2048 + bl*16 + hp*4);
      const float kk = Sb - 2.f*psum;
      const int st = e & 3;
      float ze;
      if (st == 0){      av = kk;        ze = zb + C2*kk; }
      else if (st == 1){ av += 2.f*kk;   ze = zb + C2*kk; }
      else if (st == 2){ av += 2.f*kk;   ze = zb + HS*kk; }
      else {
        zb += C6*(av + kk); ze = zb;
        if ((e & 15) == 15)
          hT[(size_t)(bt*128 + bl)*1280 + (size_t)((e >> 4) + 1)*128 + ht*4 + hp] = zb;
      }
      *(uint16_t*)(Lds + HB + 16384 + t*2) = f2bf(ze);
    }
    __syncthreads();                            // F: zpack ready

    if (e < 143){
      // ---- publish zfrag[(e+1)&1] slice (128 B/block, XCD-local) ----
      if (t < 128){
        uint64_t zw = *(const uint64_t*)(Lds + HB + 16384 + t*8);
        char* zdst = (char*)zfG + (size_t)((e + 1) & 1)*262144 + zsl_off
                   + (t >> 4)*4096 + (ht >> 3)*1024
                   + ((t & 15) + 16*((ht & 7) >> 1))*16 + (ht & 1)*8;
        st_ic64(zdst, zw);
      }
      __syncthreads();                          // G: drain publish stores
      if (t == 0){
        __hip_atomic_fetch_add(cnt, 1u, __ATOMIC_RELAXED, __HIP_MEMORY_SCOPE_AGENT);
        int spins = 0;
        while (__hip_atomic_load(cnt, __ATOMIC_RELAXED, __HIP_MEMORY_SCOPE_AGENT) < 32u*(uint32_t)(e + 1)){
          __builtin_amdgcn_s_sleep(1);
          if (++spins > (1 << 20)) break;       // safety escape, not a hang
        }
        asm volatile("" ::: "memory");
      }
      __syncthreads();                          // H: team released
    }
  }
}

// ---------- readout ----------
__global__ __launch_bounds__(256) void pose_readout(
    const float* __restrict__ hT, const float* __restrict__ w_r1, const float* __restrict__ b_r1,
    const float* __restrict__ w_r2, const float* __restrict__ b_r2,
    float* __restrict__ out_poses, float* __restrict__ out_z)
{
  if (blockIdx.x >= 320){
    const int cb = blockIdx.x - 320;
    const int base = cb*2048 + threadIdx.x*4;
    #pragma unroll
    for (int p = 0; p < 2; p++){
      const int i = base + p*1024;
      const int b = i >> 7, h = i & 127;
      *(f32x4*)(out_z + i) = *(const f32x4*)(hT + (size_t)b*1280 + 1152 + h);
    }
    return;
  }
  __shared__ float htl[128][32];
  __shared__ float al[32][128];
  const int r0 = blockIdx.x * 32;
  const int t = threadIdx.x;
  { const int row = t >> 3, ch = (t & 7)*16;
    #pragma unroll
    for (int j = 0; j < 16; j++)
      htl[ch + j][row] = hT[(size_t)(r0 + row)*128 + ch + j];
  }
  __syncthreads();
  const int j = t & 127, rg = t >> 7;
  float a[16];
  const float bj = b_r1[j];
  #pragma unroll
  for (int r = 0; r < 16; r++) a[r] = bj;
  #pragma unroll 2
  for (int kk = 0; kk < 128; kk++){
    const float wv = w_r1[(size_t)kk*128 + j];
    const float* pr = &htl[kk][rg*16];
    #pragma unroll
    for (int q = 0; q < 4; q++){
      f32x4 v = *(const f32x4*)(pr + q*4);
      a[q*4+0] += v.x*wv; a[q*4+1] += v.y*wv; a[q*4+2] += v.z*wv; a[q*4+3] += v.w*wv;
    }
  }
  #pragma unroll
  for (int r = 0; r < 16; r++){
    float v = a[r];
    al[rg*16 + r][j] = (v > 0.f) ? v : 0.1f*v;
  }
  __syncthreads();
  if (t < 192){
    const int row = t / 6, p = t % 6;
    float s = b_r2[p];
    const float* ar = al[row];
    #pragma unroll 4
    for (int jj = 0; jj < 128; jj++) s += ar[jj] * w_r2[jj*6 + p];
    out_poses[(size_t)(r0 + row)*6 + p] = s;
  }
}

// ---------- host ----------
extern "C" void kernel_launch(void* const* d_in, const int* in_sizes, int n_in,
                              void* d_out, int out_size, void* d_ws, size_t ws_size,
                              hipStream_t stream)
{
  (void)in_sizes; (void)n_in; (void)out_size; (void)ws_size;
  const float* fv    = (const float*)d_in[0];
  const float* fi    = (const float*)d_in[1];
  const float* ts    = (const float*)d_in[2];
  const float* w_red = (const float*)d_in[3];
  const float* b_red = (const float*)d_in[4];
  const float* w_init= (const float*)d_in[5];
  const float* b_init= (const float*)d_in[6];
  const float* w_h1  = (const float*)d_in[7];
  const float* b_h1  = (const float*)d_in[8];
  const float* w_h2  = (const float*)d_in[9];
  const float* b_h2  = (const float*)d_in[10];
  const float* w_out = (const float*)d_in[11];
  const float* b_out = (const float*)d_in[12];
  const float* w_r1  = (const float*)d_in[13];
  const float* b_r1  = (const float*)d_in[14];
  const float* w_r2  = (const float*)d_in[15];
  const float* b_r2  = (const float*)d_in[16];

  char* p = (char*)d_ws;
  auto take = [&](size_t n){ char* r = p; p += (n + 255) & ~(size_t)255; return r; };
  uint32_t* bar   = (uint32_t*)take(4096);
  uint16_t* Wg    = (uint16_t*)take((size_t)32*131072);   // per-ht LDS images (4MB)
  uint16_t* w0f   = (uint16_t*)take((size_t)32*4096);     // c0-tile A-frags per ht
  uint32_t* w1f   = (uint32_t*)take(32768);               // chain A-frags
  uint32_t* w2f   = (uint32_t*)take(32768);
  float* bo_f     = (float*)take((size_t)128*128*4);
  float* bo_t     = (float*)take(128*4);
  float* d0f      = (float*)take((size_t)128*1024*4);     // [c'][b]
  float* d0t      = (float*)take(1024*4);
  float* Sv       = (float*)take(1024*4);
  float* F0       = (float*)take((size_t)1024*128*4);
  float* z_base   = (float*)take((size_t)1024*128*4);
  uint16_t* zfG   = (uint16_t*)take((size_t)2*262144);    // ping-pong zfrag
  float* hT       = (float*)take((size_t)1024*10*128*4);

  float* out_poses = (float*)d_out;
  float* out_z     = (float*)d_out + 61440;

  hipMemsetAsync(bar, 0, 4096, stream);
  hipMemsetAsync(w0f, 0, (size_t)32*4096*2, stream);
  pose_convW<<<260, 256, 0, stream>>>(w_out, Wg, w0f);
  pose_convC<<<2,   256, 0, stream>>>(w_h1, w_h2, w1f, w2f);
  pose_misc <<<65,  256, 0, stream>>>(b_out, ts, bo_f, bo_t, d0t);
  pose_fused<<<128, 256, 0, stream>>>(fv, fi, w_red, b_red, F0, d0f);
  pose_init <<<16,  512, 0, stream>>>(F0, ts, w_init, b_init, d0f, d0t, z_base, zfG, hT, Sv);

  pose_persist<<<256, 1024, 0, stream>>>(Wg, w1f, w2f, w0f, b_h1, b_h2, bo_f, bo_t,
                                         d0f, d0t, Sv, z_base, zfG, hT, bar);

  pose_readout<<<384, 256, 0, stream>>>(hT, w_r1, b_r1, w_r2, b_r2, out_poses, out_z);
}

// Round 10
// 2662.811 us; speedup vs baseline: 1.9187x; 1.5562x over previous
//
#include <hip/hip_runtime.h>
#include <stdint.h>

typedef float   f32x4 __attribute__((ext_vector_type(4)));
typedef float   f32x2 __attribute__((ext_vector_type(2)));
typedef int     i32x4 __attribute__((ext_vector_type(4)));
typedef int     i32x2 __attribute__((ext_vector_type(2)));
typedef __bf16  bf16x8 __attribute__((ext_vector_type(8)));

#define DEV __device__ __forceinline__

// ---------- helpers ----------
DEV uint16_t f2bf(float f){                       // RNE f32->bf16
  uint32_t u = __float_as_uint(f);
  u += 0x7fffu + ((u >> 16) & 1u);
  return (uint16_t)(u >> 16);
}
DEV uint32_t pkbf(float lo, float hi){            // pack 2 bf16 into u32
  uint32_t r;
  asm("v_cvt_pk_bf16_f32 %0, %1, %2" : "=v"(r) : "v"(lo), "v"(hi));
  return r;
}
// byte offset inside a [row][128 bf16] (256B) row with XOR-16B bank swizzle
DEV uint32_t aoff(uint32_t row, uint32_t q){ return (row << 8) + (q ^ ((row & 7u) << 4)); }

DEV f32x4 MFMA(bf16x8 a, bf16x8 b, f32x4 c){
  return __builtin_amdgcn_mfma_f32_16x16x32_bf16(a, b, c, 0, 0, 0);
}
DEV bf16x8 as_bf(i32x4 v){ union { i32x4 i; bf16x8 b; } u; u.i = v; return u.b; }

DEV uint64_t ld_ic64(const void* p){
  return __hip_atomic_load((const uint64_t*)p, __ATOMIC_RELAXED, __HIP_MEMORY_SCOPE_AGENT);
}
DEV void st_ic64(void* p, uint64_t v){
  __hip_atomic_store((uint64_t*)p, v, __ATOMIC_RELAXED, __HIP_MEMORY_SCOPE_AGENT);
}

// ---------- W_out -> per-ht LDS images (Wg) + c0-tile frags (w0f), scaled ----------
// src [128 k][16512 n], n = h*129 + c. c>=1: row r=(c-1)*4+(h&3), image ht=h>>2.
__global__ __launch_bounds__(256) void pose_convW(const float* __restrict__ src,
    uint16_t* __restrict__ Wg, uint16_t* __restrict__ w0f)
{
  __shared__ float tile[32][256];
  const float SC = 2.8853900817779268f;   // 2*log2(e)
  int bk = blockIdx.x & 3, bn = blockIdx.x >> 2;
  int k0 = bk * 32, n0 = bn * 256;
  int t = threadIdx.x;
  for (int r = 0; r < 32; r++){
    int n = n0 + t;
    tile[r][t] = (n < 16512) ? src[(size_t)(k0 + r) * 16512 + n] : 0.f;
  }
  __syncthreads();
  int n = n0 + t;
  if (n < 16512){
    int c = n % 129, hfull = n / 129;
    int ht = hfull >> 2;
    #pragma unroll
    for (int o = 0; o < 4; o++){
      uint32_t w0 = (uint32_t)f2bf(tile[o*8+0][t]*SC) | ((uint32_t)f2bf(tile[o*8+1][t]*SC) << 16);
      uint32_t w1 = (uint32_t)f2bf(tile[o*8+2][t]*SC) | ((uint32_t)f2bf(tile[o*8+3][t]*SC) << 16);
      uint32_t w2 = (uint32_t)f2bf(tile[o*8+4][t]*SC) | ((uint32_t)f2bf(tile[o*8+5][t]*SC) << 16);
      uint32_t w3 = (uint32_t)f2bf(tile[o*8+6][t]*SC) | ((uint32_t)f2bf(tile[o*8+7][t]*SC) << 16);
      i32x4 val = { (int)w0, (int)w1, (int)w2, (int)w3 };
      uint32_t kg = (uint32_t)(k0 + o*8);
      if (c > 0){
        uint32_t r = (uint32_t)(c - 1)*4 + (hfull & 3);
        uint32_t byte = (uint32_t)ht*131072u + r*256u + ((kg*2u) ^ ((r & 7u) << 4));
        *(i32x4*)((char*)Wg + byte) = val;
      } else {
        uint32_t r0 = (uint32_t)(hfull & 3);
        uint32_t byte = (uint32_t)ht*4096u + (kg >> 5)*1024u + (r0 + 16u*((kg >> 3) & 3u))*16u;
        *(i32x4*)((char*)w0f + byte) = val;
      }
    }
  }
}

// ---------- chain weights -> A-frag layout: dst[Mt 8][kb 4][l 64][j 8] ----------
__global__ __launch_bounds__(256) void pose_convC(const float* __restrict__ w_h1,
    const float* __restrict__ w_h2, uint32_t* __restrict__ w1f, uint32_t* __restrict__ w2f)
{
  const float* src = blockIdx.x ? w_h2 : w_h1;
  uint32_t* dst = blockIdx.x ? w2f : w1f;
  int t = threadIdx.x;
  for (int ii = 0; ii < 32; ii++){
    int u = t*32 + ii;
    int p = u & 3, l = (u >> 2) & 63, kb = (u >> 8) & 3, Mt = u >> 10;
    int k = kb*32 + (l >> 4)*8 + 2*p;
    int n = Mt*16 + (l & 15);
    uint32_t v = (uint32_t)f2bf(src[(size_t)k*128 + n]) |
                 ((uint32_t)f2bf(src[(size_t)(k+1)*128 + n]) << 16);
    dst[u] = v;
  }
}

// ---------- bo_f[c'][h], bo_t[h], d0t[b] ----------
__global__ __launch_bounds__(256) void pose_misc(const float* __restrict__ b_out,
    const float* __restrict__ ts, float* __restrict__ bo_f, float* __restrict__ bo_t,
    float* __restrict__ d0t)
{
  const float SC = 2.8853900817779268f;
  int i = blockIdx.x * 256 + threadIdx.x;
  if (i < 16512){
    int c = i % 129, h = i / 129;
    if (c == 0) bo_t[h] = b_out[i] * SC;
    else        bo_f[(size_t)(c-1)*128 + h] = b_out[i] * SC;
  }
  if (i < 1024) d0t[i] = ts[i*12 + 2] - ts[i*12 + 1];
}

// ---------- fused rows l=0,1 (f32 exact): F0, d0f[h][b] ----------
__global__ __launch_bounds__(256) void pose_fused(
    const float* __restrict__ fv, const float* __restrict__ fi,
    const float* __restrict__ w_red, const float* __restrict__ b_red,
    float* __restrict__ F0, float* __restrict__ d0f)
{
  __shared__ float pk[128][16];
  __shared__ float res[16][128];
  const int b0 = blockIdx.x * 8;
  const int t = threadIdx.x;
  const int h = t & 127, sg = t >> 7;
  float acc[8] = {0.f,0.f,0.f,0.f,0.f,0.f,0.f,0.f};
  for (int p = 0; p < 6; p++){
    __syncthreads();
    { const int s  = t >> 4;
      const int ch = (t & 15) * 8;
      const int b  = b0 + (s & 7);
      const int ll = s >> 3;
      const int kb = p*128 + ch;
      const float* src = (kb < 512) ? (fv + ((size_t)b*11 + ll)*512 + kb)
                                    : (fi + ((size_t)b*11 + ll)*256 + (kb - 512));
      float v[8];
      #pragma unroll
      for (int j = 0; j < 8; j++) v[j] = src[j];
      #pragma unroll
      for (int j = 0; j < 8; j++) pk[ch + j][s] = v[j];
    }
    __syncthreads();
    #pragma unroll 4
    for (int kk = 0; kk < 128; kk++){
      const float wv = w_red[(size_t)(p*128 + kk)*128 + h];
      f32x4 v0 = *(const f32x4*)&pk[kk][sg*8];
      f32x4 v1 = *(const f32x4*)&pk[kk][sg*8 + 4];
      acc[0] += v0.x*wv; acc[1] += v0.y*wv; acc[2] += v0.z*wv; acc[3] += v0.w*wv;
      acc[4] += v1.x*wv; acc[5] += v1.y*wv; acc[6] += v1.z*wv; acc[7] += v1.w*wv;
    }
  }
  __syncthreads();
  const float br = b_red[h];
  #pragma unroll
  for (int si = 0; si < 8; si++) res[sg*8 + si][h] = acc[si] + br;
  __syncthreads();
  if (sg == 0){
    #pragma unroll
    for (int si = 0; si < 8; si++){
      const int b = b0 + si;
      const float f0 = res[si][h];
      const float f1 = res[8 + si][h];
      F0[(size_t)b*128 + h] = f0;
      d0f[(size_t)h*1024 + b] = f1 - f0;
    }
  }
}

// zfrag byte address for (b, h) within buffer base
DEV uint32_t zaddr(int b, int h){
  return (uint32_t)(b >> 7)*32768u + (uint32_t)((b >> 4) & 7)*4096u + (uint32_t)(h >> 5)*1024u
       + ((uint32_t)(b & 15) + 16u*(((uint32_t)h & 31u) >> 3))*16u + ((uint32_t)h & 7u)*2u;
}

// ---------- z0 = x0 @ w_init + b_init (f32); zfrag[0]; S[b] ----------
__global__ __launch_bounds__(512) void pose_init(
    const float* __restrict__ F0, const float* __restrict__ ts,
    const float* __restrict__ w_init, const float* __restrict__ b_init,
    const float* __restrict__ d0f, const float* __restrict__ d0t,
    float* __restrict__ z_base, uint16_t* __restrict__ zfG,
    float* __restrict__ hT, float* __restrict__ S)
{
  __shared__ float Ft[128][64];
  const int b0 = blockIdx.x * 64;
  const int t = threadIdx.x;
  { const int b = t >> 3, ch = (t & 7)*16;
    #pragma unroll
    for (int j = 0; j < 16; j++) Ft[ch + j][b] = F0[(size_t)(b0 + b)*128 + ch + j];
  }
  __syncthreads();
  const int h = t & 127, rg = t >> 7;
  float acc[16];
  const float w0 = w_init[h], bi = b_init[h];
  #pragma unroll
  for (int r = 0; r < 16; r++){
    const int b = b0 + rg*16 + r;
    acc[r] = (ts[b*12 + 1] - ts[b*12 + 0]) * w0 + bi;
  }
  #pragma unroll 2
  for (int j = 0; j < 128; j++){
    const float wv = w_init[(j + 1)*128 + h];
    const float* pr = &Ft[j][rg*16];
    #pragma unroll
    for (int q = 0; q < 4; q++){
      f32x4 v = *(const f32x4*)(pr + q*4);
      acc[q*4+0] += v.x*wv; acc[q*4+1] += v.y*wv; acc[q*4+2] += v.z*wv; acc[q*4+3] += v.w*wv;
    }
  }
  #pragma unroll
  for (int r = 0; r < 16; r++){
    const int b = b0 + rg*16 + r;
    const float z = acc[r];
    z_base[(size_t)b*128 + h] = z;
    hT[(size_t)b*1280 + h] = z;
    *(uint16_t*)((char*)zfG + zaddr(b, h)) = f2bf(z);
  }
  if (t < 64){
    const int b = b0 + t;
    float s = d0t[b];
    for (int j = 0; j < 128; j++) s += d0f[(size_t)j*1024 + b];
    S[b] = s;
  }
}

// ---------- persistent: 144 evals; 1024 thr; low-pressure roles (fits 64 VGPR) ----------
__global__ __launch_bounds__(1024, 1)
__attribute__((amdgpu_num_vgpr(128)))
void pose_persist(
    const uint16_t* __restrict__ Wg, const uint32_t* __restrict__ w1f,
    const uint32_t* __restrict__ w2f, const uint16_t* __restrict__ w0f,
    const float* __restrict__ b1, const float* __restrict__ b2,
    const float* __restrict__ bo_f, const float* __restrict__ bo_t,
    const float* __restrict__ d0f, const float* __restrict__ d0t,
    const float* __restrict__ Sv, const float* __restrict__ z_base,
    uint16_t* __restrict__ zfG, float* __restrict__ hT, uint32_t* __restrict__ bar)
{
  __shared__ __align__(16) char Lds[163840];    // 0..131071: W slice; 131072..: Hbuf (32 KB)
  const uint32_t HB = 131072u;
  const int t    = threadIdx.x;
  const int blk  = blockIdx.x;
  const int bt   = blk & 7;                     // b-team == XCD (32 blocks each)
  const int ht   = blk >> 3;                    // h-team (4 output h)
  const int w    = t >> 6, l = t & 63;
  const int l15  = l & 15, l4g = l >> 4;
  const int m8   = w & 7;                       // chain role: M-tile id
  const int half = w >> 3;                      // chain role: col/M half (0/1)
  const int m4   = w & 3;                       // GEMM role: M-group (8 tiles)
  const int nq   = w >> 2;                      // GEMM role: N-quarter (2 tiles)

  // ---- prologue: W slice -> LDS (once) ----
  { const i32x4* src = (const i32x4*)((const char*)Wg + (size_t)ht*131072);
    i32x4* dst = (i32x4*)Lds;
    #pragma unroll
    for (int i = 0; i < 8; i++) dst[t + 1024*i] = src[t + 1024*i];
  }

  // L1-resident per-use tables (NOT kernel-lifetime registers):
  const float* d0q  = d0f + (size_t)l4g*1024 + bt*128 + nq*32 + l15;  // + (Mt*4)<<10 + n2*16
  const float* d0tq = d0t + bt*128 + nq*32 + l15;                     // + n2*16

  // phase-B state: t<512 <-> (bl = t>>2 in team, h' = t&3)
  const int bl = t >> 2, hp = t & 3;
  const float HS = 0x1.999996p-6f;
  const float C2 = HS * 0.5f, C6 = HS / 6.f;
  float zb = 0.f, Sb = 0.f, av = 0.f;
  if (t < 512){
    zb = z_base[(size_t)(bt*128 + bl)*128 + ht*4 + hp];
    Sb = Sv[bt*128 + bl];
  }
  uint32_t* cnt = bar + bt*32;                  // per-team counter line
  const uint32_t zsl_off = (uint32_t)bt*32768u;
  __syncthreads();

  #pragma unroll 1
  for (int e = 0; e < 144; e++){
    // ---- stage z slice (32 KB) -> Hbuf, linear copy (agent loads, once per block) ----
    { const char* zsrc = (const char*)zfG + (size_t)(e & 1)*262144 + zsl_off;
      #pragma unroll
      for (int i = 0; i < 2; i++){
        union { uint64_t q[2]; i32x4 v; } u;
        u.q[0] = ld_ic64(zsrc + t*16 + i*16384);
        u.q[1] = ld_ic64(zsrc + t*16 + i*16384 + 8);
        *(i32x4*)(Lds + HB + t*16 + i*16384) = u.v;
      }
    }
    __syncthreads();                            // Z: staged

    // ---- chain1 MFMA: pack h1 to bf16 in regs (pv[4][2], 8 regs across barrier) ----
    uint32_t pv1[4][2];
    { bf16x8 w1A[4];                            // short-lived
      #pragma unroll
      for (int kb = 0; kb < 4; kb++)
        w1A[kb] = as_bf(*(const i32x4*)((const char*)w1f + (size_t)(m8*4 + kb)*1024 + l*16));
      const f32x4 b1v = *(const f32x4*)(b1 + m8*16 + l4g*4);
      #pragma unroll
      for (int nt2 = 0; nt2 < 4; nt2++){
        bf16x8 bz[4];
        #pragma unroll
        for (int kb = 0; kb < 4; kb++)
          bz[kb] = as_bf(*(const i32x4*)(Lds + HB + (uint32_t)(half*4 + nt2)*4096u + kb*1024 + l*16));
        f32x4 a = {0.f,0.f,0.f,0.f};
        #pragma unroll
        for (int kb = 0; kb < 4; kb++) a = MFMA(w1A[kb], bz[kb], a);
        pv1[nt2][0] = pkbf(fmaxf(a.x + b1v.x, 0.f), fmaxf(a.y + b1v.y, 0.f));
        pv1[nt2][1] = pkbf(fmaxf(a.z + b1v.z, 0.f), fmaxf(a.w + b1v.w, 0.f));
      }
    }
    __syncthreads();                            // A1: z fully consumed

    // ---- h1 -> Hbuf (overwrites z image) ----
    #pragma unroll
    for (int nt2 = 0; nt2 < 4; nt2++){
      const int col = half*64 + nt2*16 + l15;
      i32x2 pv = { (int)pv1[nt2][0], (int)pv1[nt2][1] };
      *(i32x2*)(Lds + HB + aoff((uint32_t)col, (uint32_t)(m8*16 + l4g*4)*2)) = pv;
    }
    __syncthreads();                            // A2: h1 ready

    // ---- chain2: h2 = relu(w2 . h1); wave (col-tile m8, M-half) ----
    bf16x8 bh1[4];
    #pragma unroll
    for (int kb = 0; kb < 4; kb++)
      bh1[kb] = as_bf(*(const i32x4*)(Lds + HB + aoff((uint32_t)(m8*16 + l15), kb*64 + l4g*16)));
    __syncthreads();                            // B: all bh1 reads done before overwrite
    #pragma unroll
    for (int i = 0; i < 4; i++){
      const int Mt = half*4 + i;
      bf16x8 a2[4];
      #pragma unroll
      for (int kb = 0; kb < 4; kb++)
        a2[kb] = as_bf(*(const i32x4*)((const char*)w2f + (size_t)(Mt*4 + kb)*1024 + l*16));
      f32x4 acc = {0.f,0.f,0.f,0.f};
      #pragma unroll
      for (int kb = 0; kb < 4; kb++) acc = MFMA(a2[kb], bh1[kb], acc);
      const f32x4 b2v = *(const f32x4*)(b2 + Mt*16 + l4g*4);
      i32x2 pv = { (int)pkbf(fmaxf(acc.x + b2v.x, 0.f), fmaxf(acc.y + b2v.y, 0.f)),
                   (int)pkbf(fmaxf(acc.z + b2v.z, 0.f), fmaxf(acc.w + b2v.w, 0.f)) };
      *(i32x2*)(Lds + HB + aoff((uint32_t)(m8*16 + l15), (uint32_t)(Mt*16 + l4g*4)*2)) = pv;
    }
    __syncthreads();                            // C: h2 ready

    // ---- big GEMM: wave (m4: 8 M-tiles, nq: 2 N-tiles) — low reg pressure ----
    f32x4 oacc[2];
    oacc[0] = (f32x4){0.f,0.f,0.f,0.f};
    oacc[1] = (f32x4){0.f,0.f,0.f,0.f};

    { bf16x8 bh2[2][4];
      #pragma unroll
      for (int n2 = 0; n2 < 2; n2++)
        #pragma unroll
        for (int kb = 0; kb < 4; kb++)
          bh2[n2][kb] = as_bf(*(const i32x4*)(Lds + HB +
              aoff((uint32_t)(nq*32 + n2*16 + l15), kb*64 + l4g*16)));

      #pragma unroll 2
      for (int i = 0; i < 8; i++){
        const int Mt = m4*8 + i;
        bf16x8 A[4];
        #pragma unroll
        for (int kb = 0; kb < 4; kb++)
          A[kb] = as_bf(*(const i32x4*)(Lds + aoff((uint32_t)(Mt*16 + l15), kb*64 + l4g*16)));
        #pragma unroll
        for (int n2 = 0; n2 < 2; n2++){
          f32x4 acc = {0.f,0.f,0.f,0.f};
          #pragma unroll
          for (int kb = 0; kb < 4; kb++) acc = MFMA(A[kb], bh2[n2][kb], acc);
          const f32x4 bo4 = *(const f32x4*)(bo_f + (size_t)(Mt*4 + l4g)*128 + ht*4);
          f32x4 rr;
          rr.x = __builtin_amdgcn_rcpf(__builtin_amdgcn_exp2f(acc.x + bo4.x) + 1.f);
          rr.y = __builtin_amdgcn_rcpf(__builtin_amdgcn_exp2f(acc.y + bo4.y) + 1.f);
          rr.z = __builtin_amdgcn_rcpf(__builtin_amdgcn_exp2f(acc.z + bo4.z) + 1.f);
          rr.w = __builtin_amdgcn_rcpf(__builtin_amdgcn_exp2f(acc.w + bo4.w) + 1.f);
          oacc[n2] += rr * d0q[((size_t)Mt << 12) + n2*16];
        }
      }
      if (m4 == 0){   // c=0 (time) channel tile
        bf16x8 A0[4];
        #pragma unroll
        for (int kb = 0; kb < 4; kb++)
          A0[kb] = as_bf(*(const i32x4*)((const char*)w0f + (size_t)ht*4096 + kb*1024 + l*16));
        const f32x4 bt4 = *(const f32x4*)(bo_t + ht*4);
        #pragma unroll
        for (int n2 = 0; n2 < 2; n2++){
          f32x4 acc = {0.f,0.f,0.f,0.f};
          #pragma unroll
          for (int kb = 0; kb < 4; kb++) acc = MFMA(A0[kb], bh2[n2][kb], acc);
          f32x4 rr;
          rr.x = __builtin_amdgcn_rcpf(__builtin_amdgcn_exp2f(acc.x + bt4.x) + 1.f);
          rr.y = __builtin_amdgcn_rcpf(__builtin_amdgcn_exp2f(acc.y + bt4.y) + 1.f);
          rr.z = __builtin_amdgcn_rcpf(__builtin_amdgcn_exp2f(acc.z + bt4.z) + 1.f);
          rr.w = __builtin_amdgcn_rcpf(__builtin_amdgcn_exp2f(acc.w + bt4.w) + 1.f);
          const float dc = (l4g == 0) ? d0tq[n2*16] : 0.f;
          oacc[n2] += rr * dc;
        }
      }
    }

    // in-wave reduce over l4g groups
    #pragma unroll
    for (int n2 = 0; n2 < 2; n2++){
      #pragma unroll
      for (int c = 0; c < 4; c++){
        float v = oacc[n2][c];
        v += __shfl_xor(v, 16, 64);
        v += __shfl_xor(v, 32, 64);
        oacc[n2][c] = v;
      }
    }
    __syncthreads();                            // D: all h2 reads done before overwrite
    if (l < 16){
      #pragma unroll
      for (int n2 = 0; n2 < 2; n2++){
        const int b = nq*32 + n2*16 + l15;
        *(f32x4*)(Lds + HB + m4*2048 + b*16) = oacc[n2];
      }
    }
    __syncthreads();                            // E: partials ready

    // ---- phase B: block-local reduce + RK4 (t<512) ----
    if (t < 512){
      float psum = 0.f;
      #pragma unroll
      for (int m = 0; m < 4; m++)
        psum += *(const float*)(Lds + HB + m*2048 + bl*16 + hp*4);
      const float kk = Sb - 2.f*psum;
      const int st = e & 3;
      float ze;
      if (st == 0){      av = kk;        ze = zb + C2*kk; }
      else if (st == 1){ av += 2.f*kk;   ze = zb + C2*kk; }
      else if (st == 2){ av += 2.f*kk;   ze = zb + HS*kk; }
      else {
        zb += C6*(av + kk); ze = zb;
        if ((e & 15) == 15)
          hT[(size_t)(bt*128 + bl)*1280 + (size_t)((e >> 4) + 1)*128 + ht*4 + hp] = zb;
      }
      *(uint16_t*)(Lds + HB + 16384 + t*2) = f2bf(ze);
    }
    __syncthreads();                            // F: zpack ready

    if (e < 143){
      // ---- publish zfrag[(e+1)&1] slice (128 B/block, XCD-local) ----
      if (t < 128){
        uint64_t zw = *(const uint64_t*)(Lds + HB + 16384 + t*8);
        char* zdst = (char*)zfG + (size_t)((e + 1) & 1)*262144 + zsl_off
                   + (t >> 4)*4096 + (ht >> 3)*1024
                   + ((t & 15) + 16*((ht & 7) >> 1))*16 + (ht & 1)*8;
        st_ic64(zdst, zw);
      }
      __syncthreads();                          // G: drain publish stores
      if (t == 0){
        __hip_atomic_fetch_add(cnt, 1u, __ATOMIC_RELAXED, __HIP_MEMORY_SCOPE_AGENT);
        int spins = 0;
        while (__hip_atomic_load(cnt, __ATOMIC_RELAXED, __HIP_MEMORY_SCOPE_AGENT) < 32u*(uint32_t)(e + 1)){
          __builtin_amdgcn_s_sleep(1);
          if (++spins > (1 << 20)) break;       // safety escape, not a hang
        }
        asm volatile("" ::: "memory");
      }
      __syncthreads();                          // H: team released
    }
  }
}

// ---------- readout ----------
__global__ __launch_bounds__(256) void pose_readout(
    const float* __restrict__ hT, const float* __restrict__ w_r1, const float* __restrict__ b_r1,
    const float* __restrict__ w_r2, const float* __restrict__ b_r2,
    float* __restrict__ out_poses, float* __restrict__ out_z)
{
  if (blockIdx.x >= 320){
    const int cb = blockIdx.x - 320;
    const int base = cb*2048 + threadIdx.x*4;
    #pragma unroll
    for (int p = 0; p < 2; p++){
      const int i = base + p*1024;
      const int b = i >> 7, h = i & 127;
      *(f32x4*)(out_z + i) = *(const f32x4*)(hT + (size_t)b*1280 + 1152 + h);
    }
    return;
  }
  __shared__ float htl[128][32];
  __shared__ float al[32][128];
  const int r0 = blockIdx.x * 32;
  const int t = threadIdx.x;
  { const int row = t >> 3, ch = (t & 7)*16;
    #pragma unroll
    for (int j = 0; j < 16; j++)
      htl[ch + j][row] = hT[(size_t)(r0 + row)*128 + ch + j];
  }
  __syncthreads();
  const int j = t & 127, rg = t >> 7;
  float a[16];
  const float bj = b_r1[j];
  #pragma unroll
  for (int r = 0; r < 16; r++) a[r] = bj;
  #pragma unroll 2
  for (int kk = 0; kk < 128; kk++){
    const float wv = w_r1[(size_t)kk*128 + j];
    const float* pr = &htl[kk][rg*16];
    #pragma unroll
    for (int q = 0; q < 4; q++){
      f32x4 v = *(const f32x4*)(pr + q*4);
      a[q*4+0] += v.x*wv; a[q*4+1] += v.y*wv; a[q*4+2] += v.z*wv; a[q*4+3] += v.w*wv;
    }
  }
  #pragma unroll
  for (int r = 0; r < 16; r++){
    float v = a[r];
    al[rg*16 + r][j] = (v > 0.f) ? v : 0.1f*v;
  }
  __syncthreads();
  if (t < 192){
    const int row = t / 6, p = t % 6;
    float s = b_r2[p];
    const float* ar = al[row];
    #pragma unroll 4
    for (int jj = 0; jj < 128; jj++) s += ar[jj] * w_r2[jj*6 + p];
    out_poses[(size_t)(r0 + row)*6 + p] = s;
  }
}

// ---------- host ----------
extern "C" void kernel_launch(void* const* d_in, const int* in_sizes, int n_in,
                              void* d_out, int out_size, void* d_ws, size_t ws_size,
                              hipStream_t stream)
{
  (void)in_sizes; (void)n_in; (void)out_size; (void)ws_size;
  const float* fv    = (const float*)d_in[0];
  const float* fi    = (const float*)d_in[1];
  const float* ts    = (const float*)d_in[2];
  const float* w_red = (const float*)d_in[3];
  const float* b_red = (const float*)d_in[4];
  const float* w_init= (const float*)d_in[5];
  const float* b_init= (const float*)d_in[6];
  const float* w_h1  = (const float*)d_in[7];
  const float* b_h1  = (const float*)d_in[8];
  const float* w_h2  = (const float*)d_in[9];
  const float* b_h2  = (const float*)d_in[10];
  const float* w_out = (const float*)d_in[11];
  const float* b_out = (const float*)d_in[12];
  const float* w_r1  = (const float*)d_in[13];
  const float* b_r1  = (const float*)d_in[14];
  const float* w_r2  = (const float*)d_in[15];
  const float* b_r2  = (const float*)d_in[16];

  char* p = (char*)d_ws;
  auto take = [&](size_t n){ char* r = p; p += (n + 255) & ~(size_t)255; return r; };
  uint32_t* bar   = (uint32_t*)take(4096);
  uint16_t* Wg    = (uint16_t*)take((size_t)32*131072);   // per-ht LDS images (4MB)
  uint16_t* w0f   = (uint16_t*)take((size_t)32*4096);     // c0-tile A-frags per ht
  uint32_t* w1f   = (uint32_t*)take(32768);               // chain A-frags
  uint32_t* w2f   = (uint32_t*)take(32768);
  float* bo_f     = (float*)take((size_t)128*128*4);
  float* bo_t     = (float*)take(128*4);
  float* d0f      = (float*)take((size_t)128*1024*4);     // [c'][b]
  float* d0t      = (float*)take(1024*4);
  float* Sv       = (float*)take(1024*4);
  float* F0       = (float*)take((size_t)1024*128*4);
  float* z_base   = (float*)take((size_t)1024*128*4);
  uint16_t* zfG   = (uint16_t*)take((size_t)2*262144);    // ping-pong zfrag
  float* hT       = (float*)take((size_t)1024*10*128*4);

  float* out_poses = (float*)d_out;
  float* out_z     = (float*)d_out + 61440;

  hipMemsetAsync(bar, 0, 4096, stream);
  hipMemsetAsync(w0f, 0, (size_t)32*4096*2, stream);
  pose_convW<<<260, 256, 0, stream>>>(w_out, Wg, w0f);
  pose_convC<<<2,   256, 0, stream>>>(w_h1, w_h2, w1f, w2f);
  pose_misc <<<65,  256, 0, stream>>>(b_out, ts, bo_f, bo_t, d0t);
  pose_fused<<<128, 256, 0, stream>>>(fv, fi, w_red, b_red, F0, d0f);
  pose_init <<<16,  512, 0, stream>>>(F0, ts, w_init, b_init, d0f, d0t, z_base, zfG, hT, Sv);

  pose_persist<<<256, 1024, 0, stream>>>(Wg, w1f, w2f, w0f, b_h1, b_h2, bo_f, bo_t,
                                         d0f, d0t, Sv, z_base, zfG, hT, bar);

  pose_readout<<<384, 256, 0, stream>>>(hT, w_r1, b_r1, w_r2, b_r2, out_poses, out_z);
}